// Round 2
// baseline (906.688 us; speedup 1.0000x reference)
//
#include <hip/hip_runtime.h>
#include <stdint.h>

// Problem constants (B=2, H=16, S=2048, D=64)
constexpr int S   = 2048;
constexpr int D   = 64;
constexpr int BH  = 32;      // B*H
constexpr int QT  = 64;      // q rows per block (16 per wave)
constexpr int KT  = 64;      // k rows per tile
constexpr int LDP = 72;      // padded LDS row length in shorts (vt_kernel only)

using short8  = __attribute__((ext_vector_type(8))) short;
using float4v = __attribute__((ext_vector_type(4))) float;

static __device__ __forceinline__ unsigned short f2bf(float f) {
    union { float f; unsigned u; } x; x.f = f;
    unsigned u = x.u;
    u += 0x7fffu + ((u >> 16) & 1u);   // round-to-nearest-even
    return (unsigned short)(u >> 16);
}

// packed f32x2 -> bf16x2 (RNE), single instruction
static __device__ __forceinline__ unsigned cvt_pk_bf16(float lo, float hi) {
    unsigned r;
    asm("v_cvt_pk_bf16_f32 %0, %1, %2" : "=v"(r) : "v"(lo), "v"(hi));
    return r;
}

// ---------------------------------------------------------------------------
// Pre-kernel A: K bf16 row-major copy (amortizes f32->bf16 over 64 re-reads)
// ---------------------------------------------------------------------------
__global__ __launch_bounds__(256) void cvt_kernel(const float* __restrict__ src,
                                                  unsigned short* __restrict__ dst) {
#pragma unroll
    for (int i = 0; i < 4; ++i) {
        const size_t f4 = (size_t)blockIdx.x * 1024 + i * 256 + threadIdx.x;
        float4v val = ((const float4v*)src)[f4];
        ushort4 pk;
        pk.x = f2bf(val.x);
        pk.y = f2bf(val.y);
        pk.z = f2bf(val.z);
        pk.w = f2bf(val.w);
        ((ushort4*)dst)[f4] = pk;
    }
}

// ---------------------------------------------------------------------------
// Pre-kernel B: Vt[bh][d][k] = bf16(V[bh][k][d])
// ---------------------------------------------------------------------------
__global__ __launch_bounds__(256) void vt_kernel(const float* __restrict__ v,
                                                 unsigned short* __restrict__ vt) {
    __shared__ __align__(16) unsigned short sT[64][LDP];
    const int blk = blockIdx.x;          // 0..1023
    const int bh  = blk >> 5;            // 0..31
    const int k0  = (blk & 31) << 6;     // 0,64,...,1984
    const int t   = threadIdx.x;
    const float* vp = v + ((size_t)bh * S + k0) * D;
#pragma unroll
    for (int i = 0; i < 4; ++i) {
        const int f4 = t + 256 * i;
        float4v val = ((const float4v*)vp)[f4];
        const int e = f4 * 4;
        const int r = e >> 6;
        const int c = e & 63;
        sT[c + 0][r] = f2bf(val.x);
        sT[c + 1][r] = f2bf(val.y);
        sT[c + 2][r] = f2bf(val.z);
        sT[c + 3][r] = f2bf(val.w);
    }
    __syncthreads();
#pragma unroll
    for (int i = 0; i < 2; ++i) {
        const int f    = t + 256 * i;
        const int drow = f >> 3;
        const int kc   = (f & 7) * 8;
        short8 val = *(const short8*)&sT[drow][kc];
        *(short8*)(vt + ((size_t)bh * D + drow) * S + k0 + kc) = val;
    }
}

// ---------------------------------------------------------------------------
// Main fused attention kernel — ZERO LDS, ZERO barriers.
// 256 threads (4 waves), 64 q rows per block (16 per wave), fully independent
// waves. K/Vt MFMA fragments are 16B-contiguous in global memory and L1/L2-hot
// (256KB panels per bh; XCD swizzle keeps 4 bh = 2MB per XCD L2).
//
// QK^T is computed SWAPPED: cf[nc] = mfma(Kfrag, Qfrag) = S^T tile, so
//   cf[nc][r] = S[k = k0+nc*16+quad*4+r][q = q0+wave*16+n16]
// making each lane own one q-column => rowsum = 2 shfl_xor, attn stores are
// direct float4 writes, and P->A-fragment conversion is an in-register
// 2-stage xor-shuffle butterfly (no sP LDS round-trip).
// ---------------------------------------------------------------------------
__global__ __launch_bounds__(256, 4) void attn_kernel(const float* __restrict__ q,
                                                      const unsigned short* __restrict__ kb,
                                                      const int* __restrict__ mask,
                                                      const unsigned short* __restrict__ vt,
                                                      float* __restrict__ out) {
    const int tid  = threadIdx.x;
    const int wave = tid >> 6;
    const int lane = tid & 63;
    const int quad = lane >> 4;
    const int n16  = lane & 15;

    // XCD-contiguous remap: 1024 blocks, 8 XCDs, 128 blocks (4 bh) per XCD.
    const int bx0 = blockIdx.x;
    const int bx  = (bx0 & 7) * 128 + (bx0 >> 3);
    const int bh  = bx >> 5;        // 0..31
    const int qt  = bx & 31;
    const int q0  = qt * QT;
    const int b   = bh >> 4;        // batch index (H=16)

    const float* qp = q + ((size_t)bh * S + q0) * D;
    const unsigned short* kp  = kb + (size_t)bh * S * D;
    const unsigned short* vtp = vt + (size_t)bh * D * S;
    const int* mp = mask + b * S;

    // ---- Q A-fragments direct from global, scaled by 1/8, bf16 ----
    // aq_c element j = bf16( Q[q0+wave*16+n16][c*32+quad*8+j] / 8 )
    short8 aq0, aq1;
    {
        const float4v* qrow = (const float4v*)(qp + (size_t)(wave * 16 + n16) * D);
        float4v a = qrow[quad * 2], bq = qrow[quad * 2 + 1];
        float4v c = qrow[8 + quad * 2], d = qrow[8 + quad * 2 + 1];
        union { short8 s8; unsigned short u[8]; } t0, t1;
        t0.u[0] = f2bf(a.x * 0.125f);  t0.u[1] = f2bf(a.y * 0.125f);
        t0.u[2] = f2bf(a.z * 0.125f);  t0.u[3] = f2bf(a.w * 0.125f);
        t0.u[4] = f2bf(bq.x * 0.125f); t0.u[5] = f2bf(bq.y * 0.125f);
        t0.u[6] = f2bf(bq.z * 0.125f); t0.u[7] = f2bf(bq.w * 0.125f);
        t1.u[0] = f2bf(c.x * 0.125f);  t1.u[1] = f2bf(c.y * 0.125f);
        t1.u[2] = f2bf(c.z * 0.125f);  t1.u[3] = f2bf(c.w * 0.125f);
        t1.u[4] = f2bf(d.x * 0.125f);  t1.u[5] = f2bf(d.y * 0.125f);
        t1.u[6] = f2bf(d.z * 0.125f);  t1.u[7] = f2bf(d.w * 0.125f);
        aq0 = t0.s8; aq1 = t1.s8;
    }

    float4v accO[4];
    const float4v zero4 = {0.f, 0.f, 0.f, 0.f};
#pragma unroll
    for (int nv = 0; nv < 4; ++nv) accO[nv] = zero4;
    float lsum = 0.f;   // running sum for q = q0 + wave*16 + n16

    // =========================== Loop 1 ===========================
    for (int kt = 0; kt < S / KT; ++kt) {
        const int k0 = kt * KT;

        // QK^T (swapped): A = K rows, B = Q rows
        float4v cf[4];
#pragma unroll
        for (int nc = 0; nc < 4; ++nc) cf[nc] = zero4;
        __builtin_amdgcn_s_setprio(1);
#pragma unroll
        for (int c = 0; c < 2; ++c) {
            const short8 aq = (c == 0) ? aq0 : aq1;
#pragma unroll
            for (int nc = 0; nc < 4; ++nc) {
                const short8 kf = *(const short8*)(kp + (size_t)(k0 + nc * 16 + n16) * D + c * 32 + quad * 8);
                cf[nc] = __builtin_amdgcn_mfma_f32_16x16x32_bf16(kf, aq, cf[nc], 0, 0, 0);
            }
        }
        __builtin_amdgcn_s_setprio(0);

        // p = exp(s) * mask(k);  k = k0 + nc*16 + quad*4 + r
        float p[4][4];
#pragma unroll
        for (int nc = 0; nc < 4; ++nc) {
            const int4 m4 = *(const int4*)(mp + k0 + nc * 16 + quad * 4);
            p[nc][0] = m4.x ? __expf(cf[nc][0]) : 0.f;
            p[nc][1] = m4.y ? __expf(cf[nc][1]) : 0.f;
            p[nc][2] = m4.z ? __expf(cf[nc][2]) : 0.f;
            p[nc][3] = m4.w ? __expf(cf[nc][3]) : 0.f;
        }
        // row sum for q=n16: local 16 values, then reduce across quads
        {
            float s = 0.f;
#pragma unroll
            for (int nc = 0; nc < 4; ++nc)
#pragma unroll
                for (int r = 0; r < 4; ++r) s += p[nc][r];
            s += __shfl_xor(s, 16, 64);
            s += __shfl_xor(s, 32, 64);
            lsum += s;
        }

        // ---- P (swapped C-layout) -> PV A-fragments, fully in-register ----
        // w[nc*2+t] = bf16 pair for k = k0 + nc*16 + quad*4 + 2t (+1)
        unsigned w[8];
#pragma unroll
        for (int nc = 0; nc < 4; ++nc) {
            w[nc * 2 + 0] = cvt_pk_bf16(p[nc][0], p[nc][1]);
            w[nc * 2 + 1] = cvt_pk_bf16(p[nc][2], p[nc][3]);
        }
        // X = even-nc dwords, Y = odd-nc dwords (4 each)
        // 2-stage butterfly: every direction carries useful data.
        //  ^32: q0 sends Y0->q2(keep), q2 sends X2->q0(relay), q1 sends Y1->q3(relay), q3 sends X3->q1(keep)
        //  ^16: q0 sends r1(X2)->q1, q1 sends X1->q0, q2 sends Y2->q3, q3 sends r1(Y1)->q2
        unsigned X[4] = { w[0], w[1], w[4], w[5] };
        unsigned Y[4] = { w[2], w[3], w[6], w[7] };
        unsigned r1[4], r2[4];
#pragma unroll
        for (int d = 0; d < 4; ++d) {
            const unsigned send1 = (quad & 2) ? X[d] : Y[d];
            r1[d] = (unsigned)__shfl_xor((int)send1, 32, 64);
        }
#pragma unroll
        for (int d = 0; d < 4; ++d) {
            const unsigned send2 = (quad == 1) ? X[d] : (quad == 2) ? Y[d] : r1[d];
            r2[d] = (unsigned)__shfl_xor((int)send2, 16, 64);
        }
        // Assemble ap[kc]: lane needs P[q=n16][k = k0 + kc*32 + quad*8 + j]
        union { short8 s8; unsigned u[4]; } ap0, ap1;
        ap0.u[0] = (quad == 0) ? w[0] : (quad == 2) ? r1[0] : r2[0];
        ap0.u[1] = (quad == 0) ? w[1] : (quad == 2) ? r1[1] : r2[1];
        ap0.u[2] = (quad == 3) ? w[2] : (quad == 1) ? r1[0] : r2[0];
        ap0.u[3] = (quad == 3) ? w[3] : (quad == 1) ? r1[1] : r2[1];
        ap1.u[0] = (quad == 0) ? w[4] : (quad == 2) ? r1[2] : r2[2];
        ap1.u[1] = (quad == 0) ? w[5] : (quad == 2) ? r1[3] : r2[3];
        ap1.u[2] = (quad == 3) ? w[6] : (quad == 1) ? r1[2] : r2[2];
        ap1.u[3] = (quad == 3) ? w[7] : (quad == 1) ? r1[3] : r2[3];

        // PV: O += P @ V  (B-fragments direct from global Vt)
        __builtin_amdgcn_s_setprio(1);
#pragma unroll
        for (int kc = 0; kc < 2; ++kc) {
            const short8 ap = (kc == 0) ? ap0.s8 : ap1.s8;
#pragma unroll
            for (int nv = 0; nv < 4; ++nv) {
                const short8 bv = *(const short8*)(vtp + (size_t)(nv * 16 + n16) * S + k0 + kc * 32 + quad * 8);
                accO[nv] = __builtin_amdgcn_mfma_f32_16x16x32_bf16(ap, bv, accO[nv], 0, 0, 0);
            }
        }
        __builtin_amdgcn_s_setprio(0);
    }

    // ---- normalization factors ----
    const float linv_sw = 1.0f / lsum;            // for q = n16 (swapped layout)
    float linv_c[4];                              // for q = quad*4 + r (C-layout)
#pragma unroll
    for (int r = 0; r < 4; ++r)
        linv_c[r] = __shfl(linv_sw, quad * 4 + r, 64);

    // ---- store O ----
    {
        const size_t obase = ((size_t)bh * S + q0 + wave * 16) * D;
#pragma unroll
        for (int nv = 0; nv < 4; ++nv)
#pragma unroll
            for (int r = 0; r < 4; ++r)
                out[obase + (size_t)(quad * 4 + r) * D + nv * 16 + n16] = accO[nv][r] * linv_c[r];
    }

    // ====== Loop 2: attn = exp*mask*linv, swapped layout -> float4 stores ======
    float* attn = out + (size_t)BH * S * D;
    const size_t arow = (size_t)bh * S * S + (size_t)(q0 + wave * 16 + n16) * S;
    for (int kt = 0; kt < S / KT; ++kt) {
        const int k0 = kt * KT;
        float4v cf[4];
#pragma unroll
        for (int nc = 0; nc < 4; ++nc) cf[nc] = zero4;
        __builtin_amdgcn_s_setprio(1);
#pragma unroll
        for (int c = 0; c < 2; ++c) {
            const short8 aq = (c == 0) ? aq0 : aq1;
#pragma unroll
            for (int nc = 0; nc < 4; ++nc) {
                const short8 kf = *(const short8*)(kp + (size_t)(k0 + nc * 16 + n16) * D + c * 32 + quad * 8);
                cf[nc] = __builtin_amdgcn_mfma_f32_16x16x32_bf16(kf, aq, cf[nc], 0, 0, 0);
            }
        }
        __builtin_amdgcn_s_setprio(0);
#pragma unroll
        for (int nc = 0; nc < 4; ++nc) {
            const int4 m4 = *(const int4*)(mp + k0 + nc * 16 + quad * 4);
            float4v wv;
            wv[0] = m4.x ? __expf(cf[nc][0]) * linv_sw : 0.f;
            wv[1] = m4.y ? __expf(cf[nc][1]) * linv_sw : 0.f;
            wv[2] = m4.z ? __expf(cf[nc][2]) * linv_sw : 0.f;
            wv[3] = m4.w ? __expf(cf[nc][3]) * linv_sw : 0.f;
            *(float4v*)&attn[arow + k0 + nc * 16 + quad * 4] = wv;
        }
    }
}

// ---------------------------------------------------------------------------
extern "C" void kernel_launch(void* const* d_in, const int* in_sizes, int n_in,
                              void* d_out, int out_size, void* d_ws, size_t ws_size,
                              hipStream_t stream) {
    const float* q    = (const float*)d_in[0];
    const float* k    = (const float*)d_in[1];
    const float* v    = (const float*)d_in[2];
    const int*   mask = (const int*)d_in[3];
    // workspace: [0,8MB) K-bf16 row-major, [8MB,16MB) Vt bf16
    unsigned short* kbf = (unsigned short*)d_ws;
    unsigned short* vt  = kbf + (size_t)BH * S * D;
    float* out = (float*)d_out;

    cvt_kernel<<<dim3(1024), dim3(256), 0, stream>>>(k, kbf);
    vt_kernel<<<dim3(BH * (S / 64)), dim3(256), 0, stream>>>(v, vt);
    attn_kernel<<<dim3(BH * (S / QT)), dim3(256), 0, stream>>>(q, kbf, mask, vt, out);
}

// Round 3
// 891.611 us; speedup vs baseline: 1.0169x; 1.0169x over previous
//
#include <hip/hip_runtime.h>
#include <stdint.h>

// Problem constants (B=2, H=16, S=2048, D=64)
constexpr int S   = 2048;
constexpr int D   = 64;
constexpr int BH  = 32;      // B*H
constexpr int QT  = 64;      // q rows per block (16 per wave)
constexpr int KT  = 64;      // k rows per tile
constexpr int NT  = S / KT;  // 32 k-tiles... (64 actually: 2048/64 = 32? no, =32) -- computed below
constexpr int LDP = 72;      // padded LDS row length in shorts (vt_kernel only)

using short8  = __attribute__((ext_vector_type(8))) short;
using float4v = __attribute__((ext_vector_type(4))) float;

static __device__ __forceinline__ unsigned short f2bf(float f) {
    union { float f; unsigned u; } x; x.f = f;
    unsigned u = x.u;
    u += 0x7fffu + ((u >> 16) & 1u);   // round-to-nearest-even
    return (unsigned short)(u >> 16);
}

// packed f32x2 -> bf16x2 (RNE), single instruction
static __device__ __forceinline__ unsigned cvt_pk_bf16(float lo, float hi) {
    unsigned r;
    asm("v_cvt_pk_bf16_f32 %0, %1, %2" : "=v"(r) : "v"(lo), "v"(hi));
    return r;
}

// ---------------------------------------------------------------------------
// Pre-kernel A: K bf16 row-major copy (amortizes f32->bf16 over 64 re-reads)
// ---------------------------------------------------------------------------
__global__ __launch_bounds__(256) void cvt_kernel(const float* __restrict__ src,
                                                  unsigned short* __restrict__ dst) {
#pragma unroll
    for (int i = 0; i < 4; ++i) {
        const size_t f4 = (size_t)blockIdx.x * 1024 + i * 256 + threadIdx.x;
        float4v val = ((const float4v*)src)[f4];
        ushort4 pk;
        pk.x = f2bf(val.x);
        pk.y = f2bf(val.y);
        pk.z = f2bf(val.z);
        pk.w = f2bf(val.w);
        ((ushort4*)dst)[f4] = pk;
    }
}

// ---------------------------------------------------------------------------
// Pre-kernel B: Vt[bh][d][k] = bf16(V[bh][k][d])
// ---------------------------------------------------------------------------
__global__ __launch_bounds__(256) void vt_kernel(const float* __restrict__ v,
                                                 unsigned short* __restrict__ vt) {
    __shared__ __align__(16) unsigned short sT[64][LDP];
    const int blk = blockIdx.x;          // 0..1023
    const int bh  = blk >> 5;            // 0..31
    const int k0  = (blk & 31) << 6;     // 0,64,...,1984
    const int t   = threadIdx.x;
    const float* vp = v + ((size_t)bh * S + k0) * D;
#pragma unroll
    for (int i = 0; i < 4; ++i) {
        const int f4 = t + 256 * i;
        float4v val = ((const float4v*)vp)[f4];
        const int e = f4 * 4;
        const int r = e >> 6;
        const int c = e & 63;
        sT[c + 0][r] = f2bf(val.x);
        sT[c + 1][r] = f2bf(val.y);
        sT[c + 2][r] = f2bf(val.z);
        sT[c + 3][r] = f2bf(val.w);
    }
    __syncthreads();
#pragma unroll
    for (int i = 0; i < 2; ++i) {
        const int f    = t + 256 * i;
        const int drow = f >> 3;
        const int kc   = (f & 7) * 8;
        short8 val = *(const short8*)&sT[drow][kc];
        *(short8*)(vt + ((size_t)bh * D + drow) * S + k0 + kc) = val;
    }
}

// ---------------------------------------------------------------------------
// Main fused attention kernel — ZERO LDS, ZERO barriers, register-pipelined.
// K fragments double-buffered in registers across k-tiles (issue t+1's loads
// at the top of tile t); V fragments + mask issued up-front in each body so
// their L2 latency hides under the QK^T MFMA drain + softmax VALU work.
// Swapped QK^T (mfma(K,Q) = S^T) keeps each lane owning one q-column:
// rowsum = 2 shfl_xor, attn stores are direct float4, P->A-frag is an
// in-register 2-stage xor-shuffle butterfly.
// ---------------------------------------------------------------------------
__global__ __launch_bounds__(256, 3) void attn_kernel(const float* __restrict__ q,
                                                      const unsigned short* __restrict__ kb,
                                                      const int* __restrict__ mask,
                                                      const unsigned short* __restrict__ vt,
                                                      float* __restrict__ out) {
    const int tid  = threadIdx.x;
    const int wave = tid >> 6;
    const int lane = tid & 63;
    const int quad = lane >> 4;
    const int n16  = lane & 15;

    // XCD-contiguous remap: 1024 blocks, 8 XCDs, 128 blocks (4 bh) per XCD.
    const int bx0 = blockIdx.x;
    const int bx  = (bx0 & 7) * 128 + (bx0 >> 3);
    const int bh  = bx >> 5;        // 0..31
    const int qt  = bx & 31;
    const int q0  = qt * QT;
    const int b   = bh >> 4;        // batch index (H=16)

    const float* qp = q + ((size_t)bh * S + q0) * D;
    const unsigned short* kp  = kb + (size_t)bh * S * D;
    const unsigned short* vtp = vt + (size_t)bh * D * S;
    const int* mp = mask + b * S;

    // ---- Q A-fragments direct from global, scaled by 1/8, bf16 ----
    short8 aq0, aq1;
    {
        const float4v* qrow = (const float4v*)(qp + (size_t)(wave * 16 + n16) * D);
        float4v a = qrow[quad * 2], bq = qrow[quad * 2 + 1];
        float4v c = qrow[8 + quad * 2], d = qrow[8 + quad * 2 + 1];
        union { short8 s8; unsigned short u[8]; } t0, t1;
        t0.u[0] = f2bf(a.x * 0.125f);  t0.u[1] = f2bf(a.y * 0.125f);
        t0.u[2] = f2bf(a.z * 0.125f);  t0.u[3] = f2bf(a.w * 0.125f);
        t0.u[4] = f2bf(bq.x * 0.125f); t0.u[5] = f2bf(bq.y * 0.125f);
        t0.u[6] = f2bf(bq.z * 0.125f); t0.u[7] = f2bf(bq.w * 0.125f);
        t1.u[0] = f2bf(c.x * 0.125f);  t1.u[1] = f2bf(c.y * 0.125f);
        t1.u[2] = f2bf(c.z * 0.125f);  t1.u[3] = f2bf(c.w * 0.125f);
        t1.u[4] = f2bf(d.x * 0.125f);  t1.u[5] = f2bf(d.y * 0.125f);
        t1.u[6] = f2bf(d.z * 0.125f);  t1.u[7] = f2bf(d.w * 0.125f);
        aq0 = t0.s8; aq1 = t1.s8;
    }

    // K-fragment loader: dst[c*4+nc] covers rows k0+nc*16+n16, cols c*32+quad*8..+7
    auto load_kf = [&](short8 (&dst)[8], int k0) {
#pragma unroll
        for (int c = 0; c < 2; ++c)
#pragma unroll
            for (int nc = 0; nc < 4; ++nc)
                dst[c * 4 + nc] = *(const short8*)(kp + (size_t)(k0 + nc * 16 + n16) * D + c * 32 + quad * 8);
    };

    float4v accO[4];
    const float4v zero4 = {0.f, 0.f, 0.f, 0.f};
#pragma unroll
    for (int nv = 0; nv < 4; ++nv) accO[nv] = zero4;
    float lsum = 0.f;   // running sum for q = q0 + wave*16 + n16

    short8 kfA[8], kfB[8];

    // ============ Loop 1: O accumulate + row sums (reg double-buffered) ============
    auto tile1 = [&](short8 (&kfc)[8], short8 (&kfn)[8], int k0, int k0n) {
        // prefetch next tile's K fragments (consumed next body)
        load_kf(kfn, k0n);
        // current tile's V fragments + mask: issue now, consumed after softmax
        short8 vf[8];
#pragma unroll
        for (int kc = 0; kc < 2; ++kc)
#pragma unroll
            for (int nv = 0; nv < 4; ++nv)
                vf[kc * 4 + nv] = *(const short8*)(vtp + (size_t)(nv * 16 + n16) * S + k0 + kc * 32 + quad * 8);
        int4 m4[4];
#pragma unroll
        for (int nc = 0; nc < 4; ++nc)
            m4[nc] = *(const int4*)(mp + k0 + nc * 16 + quad * 4);

        // QK^T (swapped): A = K rows, B = Q rows
        float4v cf[4];
#pragma unroll
        for (int nc = 0; nc < 4; ++nc) cf[nc] = zero4;
        __builtin_amdgcn_s_setprio(1);
#pragma unroll
        for (int c = 0; c < 2; ++c) {
            const short8 aq = (c == 0) ? aq0 : aq1;
#pragma unroll
            for (int nc = 0; nc < 4; ++nc)
                cf[nc] = __builtin_amdgcn_mfma_f32_16x16x32_bf16(kfc[c * 4 + nc], aq, cf[nc], 0, 0, 0);
        }
        __builtin_amdgcn_s_setprio(0);

        // p = exp(s) * mask(k);  k = k0 + nc*16 + quad*4 + r
        float p[4][4];
#pragma unroll
        for (int nc = 0; nc < 4; ++nc) {
            p[nc][0] = m4[nc].x ? __expf(cf[nc][0]) : 0.f;
            p[nc][1] = m4[nc].y ? __expf(cf[nc][1]) : 0.f;
            p[nc][2] = m4[nc].z ? __expf(cf[nc][2]) : 0.f;
            p[nc][3] = m4[nc].w ? __expf(cf[nc][3]) : 0.f;
        }
        {
            float s = 0.f;
#pragma unroll
            for (int nc = 0; nc < 4; ++nc)
#pragma unroll
                for (int r = 0; r < 4; ++r) s += p[nc][r];
            s += __shfl_xor(s, 16, 64);
            s += __shfl_xor(s, 32, 64);
            lsum += s;
        }

        // P (swapped C-layout) -> PV A-fragments, in-register butterfly
        unsigned w[8];
#pragma unroll
        for (int nc = 0; nc < 4; ++nc) {
            w[nc * 2 + 0] = cvt_pk_bf16(p[nc][0], p[nc][1]);
            w[nc * 2 + 1] = cvt_pk_bf16(p[nc][2], p[nc][3]);
        }
        unsigned X[4] = { w[0], w[1], w[4], w[5] };
        unsigned Y[4] = { w[2], w[3], w[6], w[7] };
        unsigned r1[4], r2[4];
#pragma unroll
        for (int dd = 0; dd < 4; ++dd) {
            const unsigned send1 = (quad & 2) ? X[dd] : Y[dd];
            r1[dd] = (unsigned)__shfl_xor((int)send1, 32, 64);
        }
#pragma unroll
        for (int dd = 0; dd < 4; ++dd) {
            const unsigned send2 = (quad == 1) ? X[dd] : (quad == 2) ? Y[dd] : r1[dd];
            r2[dd] = (unsigned)__shfl_xor((int)send2, 16, 64);
        }
        union { short8 s8; unsigned u[4]; } ap0, ap1;
        ap0.u[0] = (quad == 0) ? w[0] : (quad == 2) ? r1[0] : r2[0];
        ap0.u[1] = (quad == 0) ? w[1] : (quad == 2) ? r1[1] : r2[1];
        ap0.u[2] = (quad == 3) ? w[2] : (quad == 1) ? r1[0] : r2[0];
        ap0.u[3] = (quad == 3) ? w[3] : (quad == 1) ? r1[1] : r2[1];
        ap1.u[0] = (quad == 0) ? w[4] : (quad == 2) ? r1[2] : r2[2];
        ap1.u[1] = (quad == 0) ? w[5] : (quad == 2) ? r1[3] : r2[3];
        ap1.u[2] = (quad == 3) ? w[6] : (quad == 1) ? r1[2] : r2[2];
        ap1.u[3] = (quad == 3) ? w[7] : (quad == 1) ? r1[3] : r2[3];

        // PV: O += P @ V
        __builtin_amdgcn_s_setprio(1);
#pragma unroll
        for (int kc = 0; kc < 2; ++kc) {
            const short8 ap = (kc == 0) ? ap0.s8 : ap1.s8;
#pragma unroll
            for (int nv = 0; nv < 4; ++nv)
                accO[nv] = __builtin_amdgcn_mfma_f32_16x16x32_bf16(ap, vf[kc * 4 + nv], accO[nv], 0, 0, 0);
        }
        __builtin_amdgcn_s_setprio(0);
    };

    load_kf(kfA, 0);
    for (int kt = 0; kt < S / KT; kt += 2) {
        tile1(kfA, kfB, kt * KT, (kt + 1) * KT);
        tile1(kfB, kfA, (kt + 1) * KT, ((kt + 2) * KT) & (S - 1));   // last prefetch wraps (harmless)
    }

    // ---- normalization factors ----
    const float linv_sw = 1.0f / lsum;            // for q = n16 (swapped layout)
    float linv_c[4];                              // for q = quad*4 + r (C-layout)
#pragma unroll
    for (int r = 0; r < 4; ++r)
        linv_c[r] = __shfl(linv_sw, quad * 4 + r, 64);

    // ---- store O ----
    {
        const size_t obase = ((size_t)bh * S + q0 + wave * 16) * D;
#pragma unroll
        for (int nv = 0; nv < 4; ++nv)
#pragma unroll
            for (int r = 0; r < 4; ++r)
                out[obase + (size_t)(quad * 4 + r) * D + nv * 16 + n16] = accO[nv][r] * linv_c[r];
    }

    // ====== Loop 2: attn = exp*mask*linv, swapped layout -> float4 stores ======
    float* attn = out + (size_t)BH * S * D;
    const size_t arow = (size_t)bh * S * S + (size_t)(q0 + wave * 16 + n16) * S;

    auto tile2 = [&](short8 (&kfc)[8], short8 (&kfn)[8], int k0, int k0n) {
        load_kf(kfn, k0n);
        int4 m4[4];
#pragma unroll
        for (int nc = 0; nc < 4; ++nc)
            m4[nc] = *(const int4*)(mp + k0 + nc * 16 + quad * 4);

        float4v cf[4];
#pragma unroll
        for (int nc = 0; nc < 4; ++nc) cf[nc] = zero4;
        __builtin_amdgcn_s_setprio(1);
#pragma unroll
        for (int c = 0; c < 2; ++c) {
            const short8 aq = (c == 0) ? aq0 : aq1;
#pragma unroll
            for (int nc = 0; nc < 4; ++nc)
                cf[nc] = __builtin_amdgcn_mfma_f32_16x16x32_bf16(kfc[c * 4 + nc], aq, cf[nc], 0, 0, 0);
        }
        __builtin_amdgcn_s_setprio(0);
#pragma unroll
        for (int nc = 0; nc < 4; ++nc) {
            float4v wv;
            wv[0] = m4[nc].x ? __expf(cf[nc][0]) * linv_sw : 0.f;
            wv[1] = m4[nc].y ? __expf(cf[nc][1]) * linv_sw : 0.f;
            wv[2] = m4[nc].z ? __expf(cf[nc][2]) * linv_sw : 0.f;
            wv[3] = m4[nc].w ? __expf(cf[nc][3]) * linv_sw : 0.f;
            *(float4v*)&attn[arow + k0 + nc * 16 + quad * 4] = wv;
        }
    };

    load_kf(kfA, 0);
    for (int kt = 0; kt < S / KT; kt += 2) {
        tile2(kfA, kfB, kt * KT, (kt + 1) * KT);
        tile2(kfB, kfA, (kt + 1) * KT, ((kt + 2) * KT) & (S - 1));
    }
}

// ---------------------------------------------------------------------------
extern "C" void kernel_launch(void* const* d_in, const int* in_sizes, int n_in,
                              void* d_out, int out_size, void* d_ws, size_t ws_size,
                              hipStream_t stream) {
    const float* q    = (const float*)d_in[0];
    const float* k    = (const float*)d_in[1];
    const float* v    = (const float*)d_in[2];
    const int*   mask = (const int*)d_in[3];
    // workspace: [0,8MB) K-bf16 row-major, [8MB,16MB) Vt bf16
    unsigned short* kbf = (unsigned short*)d_ws;
    unsigned short* vt  = kbf + (size_t)BH * S * D;
    float* out = (float*)d_out;

    cvt_kernel<<<dim3(1024), dim3(256), 0, stream>>>(k, kbf);
    vt_kernel<<<dim3(BH * (S / 64)), dim3(256), 0, stream>>>(v, vt);
    attn_kernel<<<dim3(BH * (S / QT)), dim3(256), 0, stream>>>(q, kbf, mask, vt, out);
}

// Round 5
// 672.043 us; speedup vs baseline: 1.3492x; 1.3267x over previous
//
#include <hip/hip_runtime.h>
#include <stdint.h>

// Problem constants (B=2, H=16, S=2048, D=64)
constexpr int S   = 2048;
constexpr int D   = 64;
constexpr int BH  = 32;      // B*H
constexpr int QT  = 64;      // q rows per block (16 per wave)
constexpr int KT  = 64;      // k rows per tile
constexpr int NTL = S / KT;  // 32 k-tiles
constexpr int LDP = 72;      // padded LDS row (pack_kernel transpose only)

using short8  = __attribute__((ext_vector_type(8))) short;
using float4v = __attribute__((ext_vector_type(4))) float;

static __device__ __forceinline__ unsigned short f2bf(float f) {
    union { float f; unsigned u; } x; x.f = f;
    unsigned u = x.u;
    u += 0x7fffu + ((u >> 16) & 1u);   // round-to-nearest-even
    return (unsigned short)(u >> 16);
}

static __device__ __forceinline__ unsigned cvt_pk_bf16(float lo, float hi) {
    unsigned r;
    asm("v_cvt_pk_bf16_f32 %0, %1, %2" : "=v"(r) : "v"(lo), "v"(hi));
    return r;
}

// async global->LDS DMA: per-lane global src, WAVE-UNIFORM LDS base.
// HW writes lane i at ldsbase + i*16 (size=16).
static __device__ __forceinline__ void ld16(const unsigned short* g, unsigned short* ldsbase) {
    __builtin_amdgcn_global_load_lds(
        (const __attribute__((address_space(1))) void*)g,
        (__attribute__((address_space(3))) void*)ldsbase, 16, 0, 0);
}

// ---------------------------------------------------------------------------
// Pre-kernel: pack per-(bh,ktile) 16KB records into d_ws:
//   record[0:4096)  shorts = K tile  (64 rows x 64 cols bf16), XOR-swizzled
//   record[4096:8192) shorts = Vt tile (64 d-rows x 64 k-cols bf16), swizzled
// Swizzle: within each row, 16B chunk c (0..7) stored at chunk (c ^ (row&7)).
// The attn kernel DMAs the record linearly into LDS and ds_reads with the
// same XOR -> uniformly bank-distributed fragment reads.
// ---------------------------------------------------------------------------
__global__ __launch_bounds__(256) void pack_kernel(const float* __restrict__ k,
                                                   const float* __restrict__ v,
                                                   unsigned short* __restrict__ ws) {
    __shared__ __align__(16) unsigned short sT[64][LDP];
    const int blk = blockIdx.x;          // 0..1023  = bh*32 + kt
    const int bh  = blk >> 5;
    const int k0  = (blk & 31) << 6;
    const int t   = threadIdx.x;
    unsigned short* dst = ws + (size_t)blk * 8192;

    // K tile: convert + swizzled store
    const float* kp = k + ((size_t)bh * S + k0) * D;
#pragma unroll
    for (int i = 0; i < 4; ++i) {
        const int f4 = t + 256 * i;                 // 0..1023 float4 chunks
        float4v val = ((const float4v*)kp)[f4];
        const int e = f4 * 4;
        const int r = e >> 6;       // row (k-local)
        const int c = e & 63;       // col (d)
        ushort4 pk;
        pk.x = f2bf(val.x); pk.y = f2bf(val.y); pk.z = f2bf(val.z); pk.w = f2bf(val.w);
        const int idx = r * 64 + (((c >> 3) ^ (r & 7)) << 3) + (c & 7);
        *(ushort4*)&dst[idx] = pk;
    }
    // V tile: transpose via LDS, then swizzled store
    const float* vp = v + ((size_t)bh * S + k0) * D;
#pragma unroll
    for (int i = 0; i < 4; ++i) {
        const int f4 = t + 256 * i;
        float4v val = ((const float4v*)vp)[f4];
        const int e = f4 * 4;
        const int r = e >> 6;       // k-local row
        const int c = e & 63;       // d
        sT[c + 0][r] = f2bf(val.x);
        sT[c + 1][r] = f2bf(val.y);
        sT[c + 2][r] = f2bf(val.z);
        sT[c + 3][r] = f2bf(val.w);
    }
    __syncthreads();
#pragma unroll
    for (int i = 0; i < 2; ++i) {
        const int f    = t + 256 * i;    // 0..511
        const int drow = f >> 3;         // d row 0..63
        const int ch   = f & 7;          // 16B chunk within row
        short8 val = *(const short8*)&sT[drow][ch * 8];
        const int idx = 4096 + drow * 64 + ((ch ^ (drow & 7)) << 3);
        *(short8*)&dst[idx] = val;
    }
}

// ---------------------------------------------------------------------------
// Main fused attention kernel.
// 256 threads (4 waves). LDS: double-buffered 16KB tile records (K+Vt) staged
// by global_load_lds DMA; counted vmcnt (never 0 mid-loop) keeps next-tile
// DMA in flight under current-tile compute; raw s_barrier (no auto-drain).
// Swapped QK^T (mfma(K,Q)=S^T): lane owns one q-column -> rowsum = 2 shfl,
// attn stores are direct float4, P->A-frag is an in-register butterfly.
// ---------------------------------------------------------------------------
__global__ __launch_bounds__(256, 4) void attn_kernel(const float* __restrict__ q,
                                                      const unsigned short* __restrict__ ws,
                                                      const int* __restrict__ mask,
                                                      float* __restrict__ out) {
    __shared__ __align__(16) unsigned short lbuf[2][8192];   // 32 KB
    __shared__ float smF[S];                                 // 8 KB mask as float

    const int tid  = threadIdx.x;
    const int wave = tid >> 6;
    const int lane = tid & 63;
    const int quad = lane >> 4;
    const int n16  = lane & 15;

    // XCD-contiguous remap: 1024 blocks, 8 XCDs, 128 blocks (4 bh) per XCD.
    const int bx0 = blockIdx.x;
    const int bx  = (bx0 & 7) * 128 + (bx0 >> 3);
    const int bh  = bx >> 5;
    const int qt  = bx & 31;
    const int q0  = qt * QT;
    const int b   = bh >> 4;

    const float* qp = q + ((size_t)bh * S + q0) * D;
    const unsigned short* wsp = ws + (size_t)bh * NTL * 8192;

    // ---- mask -> LDS (float 0/1), once ----
    {
        const int4* mp4 = (const int4*)(mask + b * S);
#pragma unroll
        for (int i = 0; i < 2; ++i) {
            const int f = tid + 256 * i;          // 0..511 int4 chunks
            int4 m = mp4[f];
            const int e = f * 4;
            smF[e + 0] = m.x ? 1.f : 0.f;
            smF[e + 1] = m.y ? 1.f : 0.f;
            smF[e + 2] = m.z ? 1.f : 0.f;
            smF[e + 3] = m.w ? 1.f : 0.f;
        }
    }

    // ---- Q A-fragments direct from global, scaled by 1/8, bf16 ----
    short8 aq0, aq1;
    {
        const float4v* qrow = (const float4v*)(qp + (size_t)(wave * 16 + n16) * D);
        float4v a = qrow[quad * 2], bq = qrow[quad * 2 + 1];
        float4v c = qrow[8 + quad * 2], d = qrow[8 + quad * 2 + 1];
        union { short8 s8; unsigned short u[8]; } t0, t1;
        t0.u[0] = f2bf(a.x * 0.125f);  t0.u[1] = f2bf(a.y * 0.125f);
        t0.u[2] = f2bf(a.z * 0.125f);  t0.u[3] = f2bf(a.w * 0.125f);
        t0.u[4] = f2bf(bq.x * 0.125f); t0.u[5] = f2bf(bq.y * 0.125f);
        t0.u[6] = f2bf(bq.z * 0.125f); t0.u[7] = f2bf(bq.w * 0.125f);
        t1.u[0] = f2bf(c.x * 0.125f);  t1.u[1] = f2bf(c.y * 0.125f);
        t1.u[2] = f2bf(c.z * 0.125f);  t1.u[3] = f2bf(c.w * 0.125f);
        t1.u[4] = f2bf(d.x * 0.125f);  t1.u[5] = f2bf(d.y * 0.125f);
        t1.u[6] = f2bf(d.z * 0.125f);  t1.u[7] = f2bf(d.w * 0.125f);
        aq0 = t0.s8; aq1 = t1.s8;
    }

    // stagers: 16 chunks of 1KB per record; wave w covers chunks [w*4, w*4+4)
    auto stage16 = [&](int bi, int tile) {
        const unsigned short* src = wsp + (size_t)tile * 8192;
        unsigned short* dstb = &lbuf[bi][0];
#pragma unroll
        for (int j = 0; j < 4; ++j) {
            const int ch = wave * 4 + j;
            ld16(src + ch * 512 + lane * 8, dstb + ch * 512);
        }
    };
    auto stage8 = [&](int bi, int tile) {  // K half only (loop 2)
        const unsigned short* src = wsp + (size_t)tile * 8192;
        unsigned short* dstb = &lbuf[bi][0];
#pragma unroll
        for (int j = 0; j < 2; ++j) {
            const int ch = wave * 2 + j;
            ld16(src + ch * 512 + lane * 8, dstb + ch * 512);
        }
    };

    // per-lane LDS fragment offsets (shorts); row&7 == n16&7 for all frags
    int koff[2][4], voff[2][4];
#pragma unroll
    for (int c = 0; c < 2; ++c)
#pragma unroll
        for (int nc = 0; nc < 4; ++nc) {
            koff[c][nc] = (nc * 16 + n16) * 64 + (((c * 4 + quad) ^ (n16 & 7)) << 3);
            voff[c][nc] = 4096 + (nc * 16 + n16) * 64 + (((c * 4 + quad) ^ (n16 & 7)) << 3);
        }

    float4v accO[4];
    const float4v zero4 = {0.f, 0.f, 0.f, 0.f};
#pragma unroll
    for (int nv = 0; nv < 4; ++nv) accO[nv] = zero4;
    float lsum = 0.f;

    // =========================== Loop 1 ===========================
    stage16(0, 0);
    asm volatile("s_waitcnt lgkmcnt(0)" ::: "memory");   // own mask LDS writes drained
    for (int t = 0; t < NTL; ++t) {
        if (t < NTL - 1) {
            stage16((t + 1) & 1, t + 1);
            asm volatile("s_waitcnt vmcnt(4)" ::: "memory");   // tile t's DMA done; t+1 in flight
        } else {
            asm volatile("s_waitcnt vmcnt(0)" ::: "memory");
        }
        __builtin_amdgcn_sched_barrier(0);
        __builtin_amdgcn_s_barrier();                          // tile t staged for all waves

        const unsigned short* kb = &lbuf[t & 1][0];
        const int k0 = t * KT;

        // K fragments + QK^T (swapped)
        short8 kf[8];
#pragma unroll
        for (int c = 0; c < 2; ++c)
#pragma unroll
            for (int nc = 0; nc < 4; ++nc)
                kf[c * 4 + nc] = *(const short8*)&kb[koff[c][nc]];
        float4v cf[4];
#pragma unroll
        for (int nc = 0; nc < 4; ++nc) cf[nc] = zero4;
        __builtin_amdgcn_s_setprio(1);
#pragma unroll
        for (int c = 0; c < 2; ++c) {
            const short8 aq = (c == 0) ? aq0 : aq1;
#pragma unroll
            for (int nc = 0; nc < 4; ++nc)
                cf[nc] = __builtin_amdgcn_mfma_f32_16x16x32_bf16(kf[c * 4 + nc], aq, cf[nc], 0, 0, 0);
        }
        __builtin_amdgcn_s_setprio(0);

        // p = exp(s) * mask(k);  k = k0 + nc*16 + quad*4 + r
        float p[4][4];
#pragma unroll
        for (int nc = 0; nc < 4; ++nc) {
            const float4v mf = *(const float4v*)&smF[k0 + nc * 16 + quad * 4];
            p[nc][0] = __expf(cf[nc][0]) * mf[0];
            p[nc][1] = __expf(cf[nc][1]) * mf[1];
            p[nc][2] = __expf(cf[nc][2]) * mf[2];
            p[nc][3] = __expf(cf[nc][3]) * mf[3];
        }
        {
            float s = 0.f;
#pragma unroll
            for (int nc = 0; nc < 4; ++nc)
#pragma unroll
                for (int r = 0; r < 4; ++r) s += p[nc][r];
            s += __shfl_xor(s, 16, 64);
            s += __shfl_xor(s, 32, 64);
            lsum += s;
        }

        // P (swapped C-layout) -> PV A-fragments, in-register butterfly
        unsigned w[8];
#pragma unroll
        for (int nc = 0; nc < 4; ++nc) {
            w[nc * 2 + 0] = cvt_pk_bf16(p[nc][0], p[nc][1]);
            w[nc * 2 + 1] = cvt_pk_bf16(p[nc][2], p[nc][3]);
        }
        unsigned X[4] = { w[0], w[1], w[4], w[5] };
        unsigned Y[4] = { w[2], w[3], w[6], w[7] };
        unsigned r1[4], r2[4];
#pragma unroll
        for (int dd = 0; dd < 4; ++dd) {
            const unsigned send1 = (quad & 2) ? X[dd] : Y[dd];
            r1[dd] = (unsigned)__shfl_xor((int)send1, 32, 64);
        }
#pragma unroll
        for (int dd = 0; dd < 4; ++dd) {
            const unsigned send2 = (quad == 1) ? X[dd] : (quad == 2) ? Y[dd] : r1[dd];
            r2[dd] = (unsigned)__shfl_xor((int)send2, 16, 64);
        }
        union { short8 s8; unsigned u[4]; } ap0, ap1;
        ap0.u[0] = (quad == 0) ? w[0] : (quad == 2) ? r1[0] : r2[0];
        ap0.u[1] = (quad == 0) ? w[1] : (quad == 2) ? r1[1] : r2[1];
        ap0.u[2] = (quad == 3) ? w[2] : (quad == 1) ? r1[0] : r2[0];
        ap0.u[3] = (quad == 3) ? w[3] : (quad == 1) ? r1[1] : r2[1];
        ap1.u[0] = (quad == 0) ? w[4] : (quad == 2) ? r1[2] : r2[2];
        ap1.u[1] = (quad == 0) ? w[5] : (quad == 2) ? r1[3] : r2[3];
        ap1.u[2] = (quad == 3) ? w[6] : (quad == 1) ? r1[2] : r2[2];
        ap1.u[3] = (quad == 3) ? w[7] : (quad == 1) ? r1[3] : r2[3];

        // V fragments (loaded late to bound VGPR peak) + PV
        short8 vf[8];
#pragma unroll
        for (int kc = 0; kc < 2; ++kc)
#pragma unroll
            for (int nv = 0; nv < 4; ++nv)
                vf[kc * 4 + nv] = *(const short8*)&kb[voff[kc][nv]];
        __builtin_amdgcn_s_setprio(1);
#pragma unroll
        for (int kc = 0; kc < 2; ++kc) {
            const short8 ap = (kc == 0) ? ap0.s8 : ap1.s8;
#pragma unroll
            for (int nv = 0; nv < 4; ++nv)
                accO[nv] = __builtin_amdgcn_mfma_f32_16x16x32_bf16(ap, vf[kc * 4 + nv], accO[nv], 0, 0, 0);
        }
        __builtin_amdgcn_s_setprio(0);

        __builtin_amdgcn_s_barrier();   // all waves done reading buf[t&1]
    }

    // ---- normalization ----
    const float linv_sw = 1.0f / lsum;            // q = n16 (swapped layout)
    float linv_c[4];                              // q = quad*4 + r (C-layout)
#pragma unroll
    for (int r = 0; r < 4; ++r)
        linv_c[r] = __shfl(linv_sw, quad * 4 + r, 64);

    // ---- store O ----
    {
        const size_t obase = ((size_t)bh * S + q0 + wave * 16) * D;
#pragma unroll
        for (int nv = 0; nv < 4; ++nv)
#pragma unroll
            for (int r = 0; r < 4; ++r)
                out[obase + (size_t)(quad * 4 + r) * D + nv * 16 + n16] = accO[nv][r] * linv_c[r];
    }

    // ====== Loop 2: attn = exp*mask*linv, swapped layout -> float4 stores ======
    float* attn = out + (size_t)BH * S * D;
    const size_t arow = (size_t)bh * S * S + (size_t)(q0 + wave * 16 + n16) * S;

    stage8(0, 0);
    for (int t = 0; t < NTL; ++t) {
        if (t < NTL - 1) {
            stage8((t + 1) & 1, t + 1);
            asm volatile("s_waitcnt vmcnt(2)" ::: "memory");
        } else {
            asm volatile("s_waitcnt vmcnt(0)" ::: "memory");
        }
        __builtin_amdgcn_sched_barrier(0);
        __builtin_amdgcn_s_barrier();

        const unsigned short* kb = &lbuf[t & 1][0];
        const int k0 = t * KT;

        short8 kf[8];
#pragma unroll
        for (int c = 0; c < 2; ++c)
#pragma unroll
            for (int nc = 0; nc < 4; ++nc)
                kf[c * 4 + nc] = *(const short8*)&kb[koff[c][nc]];
        float4v cf[4];
#pragma unroll
        for (int nc = 0; nc < 4; ++nc) cf[nc] = zero4;
        __builtin_amdgcn_s_setprio(1);
#pragma unroll
        for (int c = 0; c < 2; ++c) {
            const short8 aq = (c == 0) ? aq0 : aq1;
#pragma unroll
            for (int nc = 0; nc < 4; ++nc)
                cf[nc] = __builtin_amdgcn_mfma_f32_16x16x32_bf16(kf[c * 4 + nc], aq, cf[nc], 0, 0, 0);
        }
        __builtin_amdgcn_s_setprio(0);
#pragma unroll
        for (int nc = 0; nc < 4; ++nc) {
            const float4v mf = *(const float4v*)&smF[k0 + nc * 16 + quad * 4];
            float4v wv;
            wv[0] = __expf(cf[nc][0]) * mf[0] * linv_sw;
            wv[1] = __expf(cf[nc][1]) * mf[1] * linv_sw;
            wv[2] = __expf(cf[nc][2]) * mf[2] * linv_sw;
            wv[3] = __expf(cf[nc][3]) * mf[3] * linv_sw;
            *(float4v*)&attn[arow + k0 + nc * 16 + quad * 4] = wv;
        }
        __builtin_amdgcn_s_barrier();
    }
}

// ---------------------------------------------------------------------------
extern "C" void kernel_launch(void* const* d_in, const int* in_sizes, int n_in,
                              void* d_out, int out_size, void* d_ws, size_t ws_size,
                              hipStream_t stream) {
    const float* q    = (const float*)d_in[0];
    const float* k    = (const float*)d_in[1];
    const float* v    = (const float*)d_in[2];
    const int*   mask = (const int*)d_in[3];
    unsigned short* ws = (unsigned short*)d_ws;   // 1024 records x 16KB = 16 MB
    float* out = (float*)d_out;

    pack_kernel<<<dim3(BH * NTL), dim3(256), 0, stream>>>(k, v, ws);
    attn_kernel<<<dim3(BH * (S / QT)), dim3(256), 0, stream>>>(q, ws, mask, out);
}

// Round 6
// 668.017 us; speedup vs baseline: 1.3573x; 1.0060x over previous
//
#include <hip/hip_runtime.h>
#include <stdint.h>

// Problem constants (B=2, H=16, S=2048, D=64)
constexpr int S   = 2048;
constexpr int D   = 64;
constexpr int BH  = 32;      // B*H
constexpr int QT  = 128;     // q rows per block (16 per wave, 8 waves)
constexpr int KT  = 64;      // k rows per tile
constexpr int NTL = S / KT;  // 32 k-tiles
constexpr int LDP = 72;      // padded LDS row (pack_kernel transpose only)

using short8  = __attribute__((ext_vector_type(8))) short;
using float4v = __attribute__((ext_vector_type(4))) float;

static __device__ __forceinline__ unsigned short f2bf(float f) {
    union { float f; unsigned u; } x; x.f = f;
    unsigned u = x.u;
    u += 0x7fffu + ((u >> 16) & 1u);   // round-to-nearest-even
    return (unsigned short)(u >> 16);
}

static __device__ __forceinline__ unsigned cvt_pk_bf16(float lo, float hi) {
    unsigned r;
    asm("v_cvt_pk_bf16_f32 %0, %1, %2" : "=v"(r) : "v"(lo), "v"(hi));
    return r;
}

// async global->LDS DMA: per-lane global src, WAVE-UNIFORM LDS base.
// HW writes lane i at ldsbase + i*16 (size=16).
static __device__ __forceinline__ void ld16(const unsigned short* g, unsigned short* ldsbase) {
    __builtin_amdgcn_global_load_lds(
        (const __attribute__((address_space(1))) void*)g,
        (__attribute__((address_space(3))) void*)ldsbase, 16, 0, 0);
}

// ---------------------------------------------------------------------------
// Pre-kernel: pack per-(bh,ktile) 16KB records into d_ws:
//   record[0:4096)  shorts = K tile  (64 rows x 64 cols bf16), XOR-swizzled
//   record[4096:8192) shorts = Vt tile (64 d-rows x 64 k-cols bf16), swizzled
// Swizzle: within each row, 16B chunk c (0..7) stored at chunk (c ^ (row&7)).
// ---------------------------------------------------------------------------
__global__ __launch_bounds__(256) void pack_kernel(const float* __restrict__ k,
                                                   const float* __restrict__ v,
                                                   unsigned short* __restrict__ ws) {
    __shared__ __align__(16) unsigned short sT[64][LDP];
    const int blk = blockIdx.x;          // 0..1023  = bh*32 + kt
    const int bh  = blk >> 5;
    const int k0  = (blk & 31) << 6;
    const int t   = threadIdx.x;
    unsigned short* dst = ws + (size_t)blk * 8192;

    // K tile: convert + swizzled store
    const float* kp = k + ((size_t)bh * S + k0) * D;
#pragma unroll
    for (int i = 0; i < 4; ++i) {
        const int f4 = t + 256 * i;                 // 0..1023 float4 chunks
        float4v val = ((const float4v*)kp)[f4];
        const int e = f4 * 4;
        const int r = e >> 6;       // row (k-local)
        const int c = e & 63;       // col (d)
        ushort4 pk;
        pk.x = f2bf(val.x); pk.y = f2bf(val.y); pk.z = f2bf(val.z); pk.w = f2bf(val.w);
        const int idx = r * 64 + (((c >> 3) ^ (r & 7)) << 3) + (c & 7);
        *(ushort4*)&dst[idx] = pk;
    }
    // V tile: transpose via LDS, then swizzled store
    const float* vp = v + ((size_t)bh * S + k0) * D;
#pragma unroll
    for (int i = 0; i < 4; ++i) {
        const int f4 = t + 256 * i;
        float4v val = ((const float4v*)vp)[f4];
        const int e = f4 * 4;
        const int r = e >> 6;       // k-local row
        const int c = e & 63;       // d
        sT[c + 0][r] = f2bf(val.x);
        sT[c + 1][r] = f2bf(val.y);
        sT[c + 2][r] = f2bf(val.z);
        sT[c + 3][r] = f2bf(val.w);
    }
    __syncthreads();
#pragma unroll
    for (int i = 0; i < 2; ++i) {
        const int f    = t + 256 * i;    // 0..511
        const int drow = f >> 3;         // d row 0..63
        const int ch   = f & 7;          // 16B chunk within row
        short8 val = *(const short8*)&sT[drow][ch * 8];
        const int idx = 4096 + drow * 64 + ((ch ^ (drow & 7)) << 3);
        *(short8*)&dst[idx] = val;
    }
}

// ---------------------------------------------------------------------------
// Main fused attention kernel.
// 512 threads (8 waves), 128 q rows per block. LDS: TRIPLE-buffered 16KB tile
// records (K+Vt) staged by global_load_lds DMA with prefetch depth 2; counted
// vmcnt (never 0 mid-loop); raw s_barrier. Each staged tile serves 128 q rows
// (2x the compute per staged byte vs QT=64).
// Swapped QK^T (mfma(K,Q)=S^T): lane owns one q-column -> rowsum = 2 shfl,
// attn stores are direct float4, P->A-frag is an in-register butterfly.
// ---------------------------------------------------------------------------
__global__ __launch_bounds__(512, 4) void attn_kernel(const float* __restrict__ q,
                                                      const unsigned short* __restrict__ ws,
                                                      const int* __restrict__ mask,
                                                      float* __restrict__ out) {
    __shared__ __align__(16) unsigned short lbuf[3][8192];   // 48 KB
    __shared__ float smF[S];                                 // 8 KB mask as float

    const int tid  = threadIdx.x;
    const int wave = tid >> 6;      // 0..7
    const int lane = tid & 63;
    const int quad = lane >> 4;
    const int n16  = lane & 15;

    // XCD-contiguous remap: 512 blocks, 8 XCDs, 64 blocks (4 bh) per XCD.
    const int bx0 = blockIdx.x;
    const int bx  = (bx0 & 7) * 64 + (bx0 >> 3);
    const int bh  = bx >> 4;        // 0..31
    const int qt  = bx & 15;        // 0..15
    const int q0  = qt * QT;
    const int b   = bh >> 4;

    const float* qp = q + ((size_t)bh * S + q0) * D;
    const unsigned short* wsp = ws + (size_t)bh * NTL * 8192;

    // ---- mask -> LDS (float 0/1), once ----
    {
        const int4* mp4 = (const int4*)(mask + b * S);
        int4 m = mp4[tid];            // 512 threads x int4 = 2048 ints
        const int e = tid * 4;
        smF[e + 0] = m.x ? 1.f : 0.f;
        smF[e + 1] = m.y ? 1.f : 0.f;
        smF[e + 2] = m.z ? 1.f : 0.f;
        smF[e + 3] = m.w ? 1.f : 0.f;
    }

    // ---- Q A-fragments direct from global, scaled by 1/8, bf16 ----
    short8 aq0, aq1;
    {
        const float4v* qrow = (const float4v*)(qp + (size_t)(wave * 16 + n16) * D);
        float4v a = qrow[quad * 2], bq = qrow[quad * 2 + 1];
        float4v c = qrow[8 + quad * 2], d = qrow[8 + quad * 2 + 1];
        union { short8 s8; unsigned short u[8]; } t0, t1;
        t0.u[0] = f2bf(a.x * 0.125f);  t0.u[1] = f2bf(a.y * 0.125f);
        t0.u[2] = f2bf(a.z * 0.125f);  t0.u[3] = f2bf(a.w * 0.125f);
        t0.u[4] = f2bf(bq.x * 0.125f); t0.u[5] = f2bf(bq.y * 0.125f);
        t0.u[6] = f2bf(bq.z * 0.125f); t0.u[7] = f2bf(bq.w * 0.125f);
        t1.u[0] = f2bf(c.x * 0.125f);  t1.u[1] = f2bf(c.y * 0.125f);
        t1.u[2] = f2bf(c.z * 0.125f);  t1.u[3] = f2bf(c.w * 0.125f);
        t1.u[4] = f2bf(d.x * 0.125f);  t1.u[5] = f2bf(d.y * 0.125f);
        t1.u[6] = f2bf(d.z * 0.125f);  t1.u[7] = f2bf(d.w * 0.125f);
        aq0 = t0.s8; aq1 = t1.s8;
    }

    // stagers: 16 chunks of 1KB per record, 8 waves
    auto stage16 = [&](int bi, int tile) {   // full record: 2 chunks/wave
        const unsigned short* src = wsp + (size_t)tile * 8192;
        unsigned short* dstb = &lbuf[bi][0];
#pragma unroll
        for (int j = 0; j < 2; ++j) {
            const int ch = wave * 2 + j;
            ld16(src + ch * 512 + lane * 8, dstb + ch * 512);
        }
    };
    auto stage8 = [&](int bi, int tile) {    // K half only: 1 chunk/wave
        const unsigned short* src = wsp + (size_t)tile * 8192;
        unsigned short* dstb = &lbuf[bi][0];
        const int ch = wave;
        ld16(src + ch * 512 + lane * 8, dstb + ch * 512);
    };

    // per-lane LDS fragment offsets (shorts)
    int koff[2][4], voff[2][4];
#pragma unroll
    for (int c = 0; c < 2; ++c)
#pragma unroll
        for (int nc = 0; nc < 4; ++nc) {
            koff[c][nc] = (nc * 16 + n16) * 64 + (((c * 4 + quad) ^ (n16 & 7)) << 3);
            voff[c][nc] = 4096 + (nc * 16 + n16) * 64 + (((c * 4 + quad) ^ (n16 & 7)) << 3);
        }

    float4v accO[4];
    const float4v zero4 = {0.f, 0.f, 0.f, 0.f};
#pragma unroll
    for (int nv = 0; nv < 4; ++nv) accO[nv] = zero4;
    float lsum = 0.f;

    // =========================== Loop 1 ===========================
    stage16(0, 0);
    stage16(1, 1);
    asm volatile("s_waitcnt lgkmcnt(0)" ::: "memory");   // own mask LDS writes drained
    for (int t = 0; t < NTL; ++t) {
        if (t + 2 < NTL) {
            stage16((t + 2) % 3, t + 2);
            asm volatile("s_waitcnt vmcnt(4)" ::: "memory");   // tile t landed; t+1,t+2 in flight
        } else if (t + 1 < NTL) {
            asm volatile("s_waitcnt vmcnt(2)" ::: "memory");
        } else {
            asm volatile("s_waitcnt vmcnt(0)" ::: "memory");
        }
        __builtin_amdgcn_sched_barrier(0);
        __builtin_amdgcn_s_barrier();                          // tile t staged for all waves

        const unsigned short* kb = &lbuf[t % 3][0];
        const int k0 = t * KT;

        // K fragments + QK^T (swapped)
        short8 kf[8];
#pragma unroll
        for (int c = 0; c < 2; ++c)
#pragma unroll
            for (int nc = 0; nc < 4; ++nc)
                kf[c * 4 + nc] = *(const short8*)&kb[koff[c][nc]];
        float4v cf[4];
#pragma unroll
        for (int nc = 0; nc < 4; ++nc) cf[nc] = zero4;
        __builtin_amdgcn_s_setprio(1);
#pragma unroll
        for (int c = 0; c < 2; ++c) {
            const short8 aq = (c == 0) ? aq0 : aq1;
#pragma unroll
            for (int nc = 0; nc < 4; ++nc)
                cf[nc] = __builtin_amdgcn_mfma_f32_16x16x32_bf16(kf[c * 4 + nc], aq, cf[nc], 0, 0, 0);
        }
        __builtin_amdgcn_s_setprio(0);

        // p = exp(s) * mask(k);  k = k0 + nc*16 + quad*4 + r
        float p[4][4];
#pragma unroll
        for (int nc = 0; nc < 4; ++nc) {
            const float4v mf = *(const float4v*)&smF[k0 + nc * 16 + quad * 4];
            p[nc][0] = __expf(cf[nc][0]) * mf[0];
            p[nc][1] = __expf(cf[nc][1]) * mf[1];
            p[nc][2] = __expf(cf[nc][2]) * mf[2];
            p[nc][3] = __expf(cf[nc][3]) * mf[3];
        }
        {
            float s = 0.f;
#pragma unroll
            for (int nc = 0; nc < 4; ++nc)
#pragma unroll
                for (int r = 0; r < 4; ++r) s += p[nc][r];
            s += __shfl_xor(s, 16, 64);
            s += __shfl_xor(s, 32, 64);
            lsum += s;
        }

        // P (swapped C-layout) -> PV A-fragments, in-register butterfly
        unsigned w[8];
#pragma unroll
        for (int nc = 0; nc < 4; ++nc) {
            w[nc * 2 + 0] = cvt_pk_bf16(p[nc][0], p[nc][1]);
            w[nc * 2 + 1] = cvt_pk_bf16(p[nc][2], p[nc][3]);
        }
        unsigned X[4] = { w[0], w[1], w[4], w[5] };
        unsigned Y[4] = { w[2], w[3], w[6], w[7] };
        unsigned r1[4], r2[4];
#pragma unroll
        for (int dd = 0; dd < 4; ++dd) {
            const unsigned send1 = (quad & 2) ? X[dd] : Y[dd];
            r1[dd] = (unsigned)__shfl_xor((int)send1, 32, 64);
        }
#pragma unroll
        for (int dd = 0; dd < 4; ++dd) {
            const unsigned send2 = (quad == 1) ? X[dd] : (quad == 2) ? Y[dd] : r1[dd];
            r2[dd] = (unsigned)__shfl_xor((int)send2, 16, 64);
        }
        union { short8 s8; unsigned u[4]; } ap0, ap1;
        ap0.u[0] = (quad == 0) ? w[0] : (quad == 2) ? r1[0] : r2[0];
        ap0.u[1] = (quad == 0) ? w[1] : (quad == 2) ? r1[1] : r2[1];
        ap0.u[2] = (quad == 3) ? w[2] : (quad == 1) ? r1[0] : r2[0];
        ap0.u[3] = (quad == 3) ? w[3] : (quad == 1) ? r1[1] : r2[1];
        ap1.u[0] = (quad == 0) ? w[4] : (quad == 2) ? r1[2] : r2[2];
        ap1.u[1] = (quad == 0) ? w[5] : (quad == 2) ? r1[3] : r2[3];
        ap1.u[2] = (quad == 3) ? w[6] : (quad == 1) ? r1[2] : r2[2];
        ap1.u[3] = (quad == 3) ? w[7] : (quad == 1) ? r1[3] : r2[3];

        // V fragments + PV
        short8 vf[8];
#pragma unroll
        for (int kc = 0; kc < 2; ++kc)
#pragma unroll
            for (int nv = 0; nv < 4; ++nv)
                vf[kc * 4 + nv] = *(const short8*)&kb[voff[kc][nv]];
        __builtin_amdgcn_s_setprio(1);
#pragma unroll
        for (int kc = 0; kc < 2; ++kc) {
            const short8 ap = (kc == 0) ? ap0.s8 : ap1.s8;
#pragma unroll
            for (int nv = 0; nv < 4; ++nv)
                accO[nv] = __builtin_amdgcn_mfma_f32_16x16x32_bf16(ap, vf[kc * 4 + nv], accO[nv], 0, 0, 0);
        }
        __builtin_amdgcn_s_setprio(0);

        __builtin_amdgcn_s_barrier();   // all waves done reading buf[t%3]
    }

    // ---- normalization ----
    const float linv_sw = 1.0f / lsum;            // q = n16 (swapped layout)
    float linv_c[4];                              // q = quad*4 + r (C-layout)
#pragma unroll
    for (int r = 0; r < 4; ++r)
        linv_c[r] = __shfl(linv_sw, quad * 4 + r, 64);

    // ---- store O ----
    {
        const size_t obase = ((size_t)bh * S + q0 + wave * 16) * D;
#pragma unroll
        for (int nv = 0; nv < 4; ++nv)
#pragma unroll
            for (int r = 0; r < 4; ++r)
                out[obase + (size_t)(quad * 4 + r) * D + nv * 16 + n16] = accO[nv][r] * linv_c[r];
    }

    // ====== Loop 2: attn = exp*mask*linv, swapped layout -> float4 stores ======
    float* attn = out + (size_t)BH * S * D;
    const size_t arow = (size_t)bh * S * S + (size_t)(q0 + wave * 16 + n16) * S;

    stage8(0, 0);
    stage8(1, 1);
    for (int t = 0; t < NTL; ++t) {
        if (t + 2 < NTL) {
            stage8((t + 2) % 3, t + 2);
            asm volatile("s_waitcnt vmcnt(2)" ::: "memory");   // leaves only t+1,t+2 loads
        } else if (t + 1 < NTL) {
            asm volatile("s_waitcnt vmcnt(1)" ::: "memory");
        } else {
            asm volatile("s_waitcnt vmcnt(0)" ::: "memory");
        }
        __builtin_amdgcn_sched_barrier(0);
        __builtin_amdgcn_s_barrier();

        const unsigned short* kb = &lbuf[t % 3][0];
        const int k0 = t * KT;

        short8 kf[8];
#pragma unroll
        for (int c = 0; c < 2; ++c)
#pragma unroll
            for (int nc = 0; nc < 4; ++nc)
                kf[c * 4 + nc] = *(const short8*)&kb[koff[c][nc]];
        float4v cf[4];
#pragma unroll
        for (int nc = 0; nc < 4; ++nc) cf[nc] = zero4;
        __builtin_amdgcn_s_setprio(1);
#pragma unroll
        for (int c = 0; c < 2; ++c) {
            const short8 aq = (c == 0) ? aq0 : aq1;
#pragma unroll
            for (int nc = 0; nc < 4; ++nc)
                cf[nc] = __builtin_amdgcn_mfma_f32_16x16x32_bf16(kf[c * 4 + nc], aq, cf[nc], 0, 0, 0);
        }
        __builtin_amdgcn_s_setprio(0);
#pragma unroll
        for (int nc = 0; nc < 4; ++nc) {
            const float4v mf = *(const float4v*)&smF[k0 + nc * 16 + quad * 4];
            float4v wv;
            wv[0] = __expf(cf[nc][0]) * mf[0] * linv_sw;
            wv[1] = __expf(cf[nc][1]) * mf[1] * linv_sw;
            wv[2] = __expf(cf[nc][2]) * mf[2] * linv_sw;
            wv[3] = __expf(cf[nc][3]) * mf[3] * linv_sw;
            *(float4v*)&attn[arow + k0 + nc * 16 + quad * 4] = wv;
        }
        __builtin_amdgcn_s_barrier();
    }
}

// ---------------------------------------------------------------------------
extern "C" void kernel_launch(void* const* d_in, const int* in_sizes, int n_in,
                              void* d_out, int out_size, void* d_ws, size_t ws_size,
                              hipStream_t stream) {
    const float* q    = (const float*)d_in[0];
    const float* k    = (const float*)d_in[1];
    const float* v    = (const float*)d_in[2];
    const int*   mask = (const int*)d_in[3];
    unsigned short* ws = (unsigned short*)d_ws;   // 1024 records x 16KB = 16 MB
    float* out = (float*)d_out;

    pack_kernel<<<dim3(BH * NTL), dim3(256), 0, stream>>>(k, v, ws);
    attn_kernel<<<dim3(BH * (S / QT)), dim3(512), 0, stream>>>(q, ws, mask, out);
}